// Round 12
// baseline (134.209 us; speedup 1.0000x reference)
//
#include <hip/hip_runtime.h>
#include <math.h>

#define BATCH 64
#define NV 1024
#define NL 512
#define DIM 512
#define TMM 256
#define TNN 256
#define BK 32
#define NKT (DIM / BK)   // 16 K-iterations

typedef __bf16 bf16x8 __attribute__((ext_vector_type(8)));
typedef float f32x4 __attribute__((ext_vector_type(4)));

__device__ __forceinline__ void gload16(const void* g, void* lds) {
    __builtin_amdgcn_global_load_lds((const __attribute__((address_space(1))) void*)g,
                                     (__attribute__((address_space(3))) void*)lds,
                                     16, 0, 0);
}

// =====================================================================
// R12: T3/T4 pipeline. fp32 staged directly to LDS via global_load_lds
// (ZERO staging registers — R4/R8 showed reg-staging can't prefetch
// within the 128-unified-reg envelope). bf16 convert + norm accumulate
// moved to fragment-read time. Loads stay in flight across barriers
// with counted vmcnt(8) (never 0 inside the loop).
//
// Per iter: vmcnt(8) -> bar1 -> ds_read fp32 frags + cvt + norm ->
// lgkmcnt(0) -> bar2 -> issue gload tile(kt+2) into the buffer just
// read -> 32 MFMA. Load->use cover = 2 barriers + full MFMA phase.
//
// LDS swizzle (T2 + m173): gload_lds writes linearly; the XOR swizzle
// byte ^= (row&7)<<4 is applied to the GLOBAL source column and the
// ds_read column, so fragment reads spread across banks (2-way = free).
// =====================================================================
__global__ __launch_bounds__(512, 2) void fused_distmin_kernel(
    const float* __restrict__ video, const float* __restrict__ lang,
    float* __restrict__ rowpart, float* __restrict__ colpart) {
    __shared__ __align__(16) char Abuf[2][TMM * BK * 4];  // 64 KB fp32
    __shared__ __align__(16) char Bbuf[2][TNN * BK * 4];  // 64 KB fp32
    __shared__ float anrm[TMM], bnrm[TNN];                // 2 KB
    // Epilogue scratch aliased onto Abuf (dead after the K-loop).
    float* rowred = (float*)Abuf;             // [2][TMM]
    float* colred = (float*)Abuf + 2 * TMM;   // [4][TNN]

    // XCD-aware swizzle: nwg = 512 = 8 XCD * 64; 8 whole batches/XCD.
    const int wg = ((blockIdx.x & 7) << 6) | (blockIdx.x >> 3);
    const int b = wg >> 3;          // 64 batches
    const int mt = (wg >> 1) & 3;   // 4 video row-blocks of 256
    const int nt = wg & 1;          // 2 lang col-blocks of 256

    const int tid = threadIdx.x;
    const int lane = tid & 63;
    const int w = tid >> 6;         // 0..7
    const int wrow = w >> 1;        // 0..3  (64-row band of A)
    const int wcol = w & 1;         // 0..1  (128-col band of B)
    const int lr = lane & 15;
    const int g = lane >> 4;        // k-octet
    const int swz = (lr & 7) << 4;  // read-side XOR swizzle (per-lane const)

    // gload geometry: thread covers rows {srcRow + 64t}, one 16B chunk.
    // Source column pre-swizzled so linear LDS + swizzled read match.
    const int srcRow = tid >> 3;                                  // 0..63
    const int srcCb = (((tid >> 3) & 7) ^ (tid & 7)) << 4;        // 0..112
    const char* aSrc = (const char*)video +
        ((size_t)(b * NV + mt * TMM + srcRow)) * DIM * 4 + srcCb;
    const char* bSrc = (const char*)lang +
        ((size_t)(b * NL + nt * TNN + srcRow)) * DIM * 4 + srcCb;
    const int dstOff = w * 1024;    // wave-uniform LDS base (+t*8192)

    float nA[4] = {0.f, 0.f, 0.f, 0.f};                      // A-norms (wcol==0)
    float nB[8] = {0.f, 0.f, 0.f, 0.f, 0.f, 0.f, 0.f, 0.f};  // B-norms (wrow==0)

    f32x4 acc[4][8];
#pragma unroll
    for (int i = 0; i < 4; i++)
#pragma unroll
        for (int j = 0; j < 8; j++) acc[i][j] = (f32x4){0.f, 0.f, 0.f, 0.f};

#define ISSUE(BUF, KT)                                                        \
    {                                                                         \
        _Pragma("unroll") for (int t = 0; t < 4; ++t) {                       \
            gload16(aSrc + (size_t)t * 64 * DIM * 4 + (size_t)(KT) * BK * 4,  \
                    &Abuf[BUF][dstOff + t * 8192]);                           \
            gload16(bSrc + (size_t)t * 64 * DIM * 4 + (size_t)(KT) * BK * 4,  \
                    &Bbuf[BUF][dstOff + t * 8192]);                           \
        }                                                                     \
    }

#define K_ITER(BUF, KISS, VMASM)                                              \
    {                                                                         \
        asm volatile(VMASM ::: "memory");                                     \
        __builtin_amdgcn_s_barrier();                                         \
        const char* Ab = Abuf[BUF];                                           \
        const char* Bb = Bbuf[BUF];                                           \
        bf16x8 av[4], bv[8];                                                  \
        _Pragma("unroll") for (int fr = 0; fr < 4; ++fr) {                    \
            const int row = wrow * 64 + fr * 16 + lr;                         \
            float4 lo = *(const float4*)(Ab + row * 128 + ((g * 32) ^ swz));  \
            float4 hi = *(const float4*)(Ab + row * 128 + ((g * 32 + 16) ^ swz)); \
            if (wcol == 0)                                                    \
                nA[fr] += lo.x * lo.x + lo.y * lo.y + lo.z * lo.z + lo.w * lo.w + \
                          hi.x * hi.x + hi.y * hi.y + hi.z * hi.z + hi.w * hi.w; \
            av[fr] = (bf16x8){(__bf16)lo.x, (__bf16)lo.y, (__bf16)lo.z, (__bf16)lo.w, \
                              (__bf16)hi.x, (__bf16)hi.y, (__bf16)hi.z, (__bf16)hi.w}; \
        }                                                                     \
        _Pragma("unroll") for (int fc = 0; fc < 8; ++fc) {                    \
            const int row = wcol * 128 + fc * 16 + lr;                        \
            float4 lo = *(const float4*)(Bb + row * 128 + ((g * 32) ^ swz));  \
            float4 hi = *(const float4*)(Bb + row * 128 + ((g * 32 + 16) ^ swz)); \
            if (wrow == 0)                                                    \
                nB[fc] += lo.x * lo.x + lo.y * lo.y + lo.z * lo.z + lo.w * lo.w + \
                          hi.x * hi.x + hi.y * hi.y + hi.z * hi.z + hi.w * hi.w; \
            bv[fc] = (bf16x8){(__bf16)lo.x, (__bf16)lo.y, (__bf16)lo.z, (__bf16)lo.w, \
                              (__bf16)hi.x, (__bf16)hi.y, (__bf16)hi.z, (__bf16)hi.w}; \
        }                                                                     \
        asm volatile("s_waitcnt lgkmcnt(0)" ::: "memory");                    \
        __builtin_amdgcn_s_barrier();                                         \
        if ((KISS) >= 0) ISSUE(BUF, KISS);                                    \
        _Pragma("unroll") for (int fr = 0; fr < 4; ++fr)                      \
            _Pragma("unroll") for (int fc = 0; fc < 8; ++fc)                  \
                acc[fr][fc] = __builtin_amdgcn_mfma_f32_16x16x32_bf16(        \
                    av[fr], bv[fc], acc[fr][fc], 0, 0, 0);                    \
    }

    // prologue: tiles 0 and 1 in flight (16 outstanding gloads/thread)
    ISSUE(0, 0);
    ISSUE(1, 1);

    // main loop: iter kt waits tile kt (vmcnt(8): tile kt+1 stays in
    // flight), reads+converts, then issues tile kt+2 into buf kt&1.
    for (int kt = 0; kt < NKT - 2; kt += 2) {
        K_ITER(0, kt + 2, "s_waitcnt vmcnt(8)");
        K_ITER(1, kt + 3, "s_waitcnt vmcnt(8)");
    }
    K_ITER(0, -1, "s_waitcnt vmcnt(8)");   // iter 14: tile 15 still in flight
    K_ITER(1, -1, "s_waitcnt vmcnt(0)");   // iter 15: drain

    // ---- norms: reduce partials across the 4 k-octets (lanes xor 16,32) ----
#pragma unroll
    for (int fr = 0; fr < 4; ++fr) {
        nA[fr] += __shfl_xor(nA[fr], 16);
        nA[fr] += __shfl_xor(nA[fr], 32);
    }
#pragma unroll
    for (int fc = 0; fc < 8; ++fc) {
        nB[fc] += __shfl_xor(nB[fc], 16);
        nB[fc] += __shfl_xor(nB[fc], 32);
    }
    if (wcol == 0 && lane < 16) {
#pragma unroll
        for (int fr = 0; fr < 4; ++fr) anrm[wrow * 64 + fr * 16 + lane] = nA[fr];
    }
    if (wrow == 0 && lane < 16) {
#pragma unroll
        for (int fc = 0; fc < 8; ++fc) bnrm[wcol * 128 + fc * 16 + lane] = nB[fc];
    }
    __syncthreads();   // Abuf dead past here -> rowred/colred alias OK

    // ---- epilogue: d = |v|^2 - 2 dot + |l|^2, row/col mins (R11-proven) ----
    const int rgrp = (lane >> 4) * 4;
    float anorm[4][4];
#pragma unroll
    for (int fr = 0; fr < 4; ++fr)
#pragma unroll
        for (int r = 0; r < 4; ++r)
            anorm[fr][r] = anrm[wrow * 64 + fr * 16 + rgrp + r];
    float bnorm[8];
#pragma unroll
    for (int fc = 0; fc < 8; ++fc)
        bnorm[fc] = bnrm[wcol * 128 + fc * 16 + lr];

    float rmin[4][4];
    float cmin[8];
#pragma unroll
    for (int fr = 0; fr < 4; ++fr)
#pragma unroll
        for (int r = 0; r < 4; ++r) rmin[fr][r] = INFINITY;
#pragma unroll
    for (int fc = 0; fc < 8; ++fc) cmin[fc] = INFINITY;

#pragma unroll
    for (int fr = 0; fr < 4; ++fr)
#pragma unroll
        for (int fc = 0; fc < 8; ++fc)
#pragma unroll
            for (int r = 0; r < 4; ++r) {
                float d = anorm[fr][r] - 2.0f * acc[fr][fc][r] + bnorm[fc];
                rmin[fr][r] = fminf(rmin[fr][r], d);
                cmin[fc] = fminf(cmin[fc], d);
            }

#pragma unroll
    for (int fr = 0; fr < 4; ++fr)
#pragma unroll
        for (int r = 0; r < 4; ++r) {
#pragma unroll
            for (int off = 1; off < 16; off <<= 1)
                rmin[fr][r] = fminf(rmin[fr][r], __shfl_xor(rmin[fr][r], off));
        }
#pragma unroll
    for (int fc = 0; fc < 8; ++fc) {
#pragma unroll
        for (int off = 16; off < 64; off <<= 1)
            cmin[fc] = fminf(cmin[fc], __shfl_xor(cmin[fc], off));
    }

    if ((lane & 15) == 0) {
#pragma unroll
        for (int fr = 0; fr < 4; ++fr)
#pragma unroll
            for (int r = 0; r < 4; ++r)
                rowred[wcol * TMM + wrow * 64 + fr * 16 + rgrp + r] = rmin[fr][r];
    }
    if (lane < 16) {
#pragma unroll
        for (int fc = 0; fc < 8; ++fc)
            colred[wrow * TNN + wcol * 128 + fc * 16 + lane] = cmin[fc];
    }
    __syncthreads();
    if (tid < TMM) {
        rowpart[((size_t)(b * 2 + nt)) * NV + mt * TMM + tid] =
            fminf(rowred[tid], rowred[TMM + tid]);
    } else {
        int c2 = tid - TMM;
        float m = INFINITY;
#pragma unroll
        for (int k = 0; k < 4; ++k) m = fminf(m, colred[k * TNN + c2]);
        colpart[((size_t)(b * 4 + mt)) * NL + nt * TNN + c2] = m;
    }
#undef K_ITER
#undef ISSUE
}

// ---------------- final reduce ----------------------------------------------
__global__ __launch_bounds__(256) void reduce2_kernel(
    const float* __restrict__ rowpart, const float* __restrict__ colpart,
    float* __restrict__ out) {
    int b = blockIdx.x;
    int tid = threadIdx.x;
    float s = 0.0f;
    for (int r = tid; r < NV; r += 256) {
        float m = fminf(rowpart[((size_t)(b * 2 + 0)) * NV + r],
                        rowpart[((size_t)(b * 2 + 1)) * NV + r]);
        s += m * (1.0f / NV);
    }
    for (int c = tid; c < NL; c += 256) {
        float m = INFINITY;
#pragma unroll
        for (int mt = 0; mt < 4; mt++)
            m = fminf(m, colpart[((size_t)(b * 4 + mt)) * NL + c]);
        s += m * (1.0f / NL);
    }
    __shared__ float red[4];
#pragma unroll
    for (int off = 32; off > 0; off >>= 1) s += __shfl_down(s, off);
    if ((tid & 63) == 0) red[tid >> 6] = s;
    __syncthreads();
    if (tid == 0) out[b] = red[0] + red[1] + red[2] + red[3];
}

// ============================================================================
extern "C" void kernel_launch(void* const* d_in, const int* in_sizes, int n_in,
                              void* d_out, int out_size, void* d_ws, size_t ws_size,
                              hipStream_t stream) {
    const float* video = (const float*)d_in[0];  // [64,1024,512] fp32
    const float* lang = (const float*)d_in[1];   // [64,512,512] fp32
    float* out = (float*)d_out;                  // [64]

    float* rowpart = (float*)d_ws;                      // 64*2*1024 floats (0.5 MB)
    float* colpart = rowpart + (size_t)BATCH * 2 * NV;  // 64*4*512 floats (0.5 MB)

    fused_distmin_kernel<<<dim3(512), 512, 0, stream>>>(video, lang, rowpart, colpart);
    reduce2_kernel<<<BATCH, 256, 0, stream>>>(rowpart, colpart, out);
}

// Round 13
// 76.106 us; speedup vs baseline: 1.7635x; 1.7635x over previous
//
#include <hip/hip_runtime.h>
#include <math.h>

#define BATCH 64
#define NV 1024
#define NL 512
#define DIM 512
#define TMM 256
#define TNN 256
#define BK 64
#define NKT (DIM / BK)   // 8 K-iterations (R13: halved chain traversals)

typedef __bf16 bf16x8 __attribute__((ext_vector_type(8)));
typedef __bf16 bf16x4 __attribute__((ext_vector_type(4)));
typedef float f32x4 __attribute__((ext_vector_type(4)));

// =====================================================================
// R13: BK=64 — the clean test of the per-iteration-latency hypothesis.
// R5/R7/R9/R11 all ran NKT=16 and all landed at 103-107 us profiled
// while traffic (1.5x), occupancy (2x), and bank conflicts (9.4M->0)
// were varied and exonerated. The one constant was 16 traversals of
// the serial chain [load-wait -> cvt+ds_write -> barrier -> ds_read ->
// MFMA -> barrier]. This round halves traversals to 8: each iteration
// is the R11 cadence twice (two 32-k sub-phases), ONE barrier/iter.
//
// Register discipline (R4/R6/R8/R10/R12 lessons): staging liveness per
// sub-phase = 8 float4 (same as R11); no load lives across a barrier;
// acc[4][8] = 128 AGPR; __launch_bounds__(512,2) only. LDS 133 KB ->
// 1 block/CU (R9/R11: occupancy does not matter in this regime).
// Bank-even lane remap (R8): SQ_LDS_BANK_CONFLICT == 0.
// =====================================================================
__global__ __launch_bounds__(512, 2) void fused_distmin_kernel(
    const float* __restrict__ video, const float* __restrict__ lang,
    float* __restrict__ rowpart, float* __restrict__ colpart) {
    // Octet-major LDS per k-half: slab o holds k = [o*8, o*8+8) of the
    // half, 16B per (o,row) entry. b128 reads / b64 writes bank-even.
    __shared__ __align__(16) ushort AsU[2][2][4][TMM][8];  // 64 KB
    __shared__ __align__(16) ushort BsU[2][2][4][TNN][8];  // 64 KB
    __shared__ float anrm[TMM], bnrm[TNN];                 // 2 KB
    // Epilogue scratch aliased onto AsU (dead after the K-loop).
    float* rowred = (float*)AsU;             // [2][TMM]
    float* colred = (float*)AsU + 2 * TMM;   // [4][TNN]

    // XCD-aware swizzle: nwg = 512 = 8 XCD * 64; 8 whole batches/XCD.
    const int wg = ((blockIdx.x & 7) << 6) | (blockIdx.x >> 3);
    const int b = wg >> 3;          // 64 batches
    const int mt = (wg >> 1) & 3;   // 4 video row-blocks of 256
    const int nt = wg & 1;          // 2 lang col-blocks of 256

    const int tid = threadIdx.x;
    const int lane = tid & 63;
    const int w = tid >> 6;         // 0..7
    const int wrow = w >> 1;        // 0..3  (64-row band of A)
    const int wcol = w & 1;         // 0..1  (128-col band of B)
    const int lr = lane & 15;
    const int g = lane >> 4;        // k-octet within a k-half

    // staging geometry (bank-even lane remap, R8-proven):
    const int half = tid & 1;            // 8B half of the 16B entry
    const int o_sl = (tid >> 4) & 3;     // LDS slab / k-octet
    const int srow = ((tid >> 6) << 3) + ((tid >> 1) & 7);  // 0..63
    const int skq = o_sl * 2 + half;     // k-quad within a 32-k half

    const float* Ath = video + ((size_t)b * NV + (size_t)mt * TMM + srow) * DIM + skq * 4;
    const float* Bth = lang + ((size_t)b * NL + (size_t)nt * TNN + srow) * DIM + skq * 4;

    float nA[4] = {0.f, 0.f, 0.f, 0.f};   // rows srow + 64t
    float nB[4] = {0.f, 0.f, 0.f, 0.f};

    f32x4 acc[4][8];
#pragma unroll
    for (int i = 0; i < 4; i++)
#pragma unroll
        for (int j = 0; j < 8; j++) acc[i][j] = (f32x4){0.f, 0.f, 0.f, 0.f};

    float4 va[4], vb[4];

    // loads one 32-k-wide chunk at absolute float column k0
    auto load_chunk = [&](int k0) {
#pragma unroll
        for (int t = 0; t < 4; ++t) {
            va[t] = *(const float4*)(Ath + (size_t)t * 64 * DIM + k0);
            vb[t] = *(const float4*)(Bth + (size_t)t * 64 * DIM + k0);
        }
    };
    auto write_chunk = [&](int buf, int kh) {
#pragma unroll
        for (int t = 0; t < 4; ++t) {
            float4 v = va[t];
            nA[t] += v.x * v.x + v.y * v.y + v.z * v.z + v.w * v.w;
            bf16x4 p = {(__bf16)v.x, (__bf16)v.y, (__bf16)v.z, (__bf16)v.w};
            *(bf16x4*)&AsU[buf][kh][o_sl][srow + 64 * t][half * 4] = p;
            float4 u = vb[t];
            nB[t] += u.x * u.x + u.y * u.y + u.z * u.z + u.w * u.w;
            bf16x4 q = {(__bf16)u.x, (__bf16)u.y, (__bf16)u.z, (__bf16)u.w};
            *(bf16x4*)&BsU[buf][kh][o_sl][srow + 64 * t][half * 4] = q;
        }
    };
    auto mfma_half = [&](int buf, int kh) {
        bf16x8 av[4], bv[8];
#pragma unroll
        for (int fr = 0; fr < 4; ++fr)
            av[fr] = *(const bf16x8*)&AsU[buf][kh][g][wrow * 64 + fr * 16 + lr][0];
#pragma unroll
        for (int fc = 0; fc < 8; ++fc)
            bv[fc] = *(const bf16x8*)&BsU[buf][kh][g][wcol * 128 + fc * 16 + lr][0];
#pragma unroll
        for (int fr = 0; fr < 4; ++fr)
#pragma unroll
            for (int fc = 0; fc < 8; ++fc)
                acc[fr][fc] = __builtin_amdgcn_mfma_f32_16x16x32_bf16(
                    av[fr], bv[fc], acc[fr][fc], 0, 0, 0);
    };

    // prologue: stage k-tile 0 (both halves) into buf 0
    load_chunk(0);
    write_chunk(0, 0);
    load_chunk(32);
    write_chunk(0, 1);
    __syncthreads();

    // main loop: each iter = two R11 sub-phases, ONE barrier.
    for (int kt = 0; kt < NKT; ++kt) {
        const int cur = kt & 1;
        const bool more = (kt + 1) < NKT;

        if (more) load_chunk((kt + 1) * BK);         // lo chunk of next tile
        mfma_half(cur, 0);
        if (more) write_chunk(cur ^ 1, 0);           // consume lo (same iter)

        if (more) load_chunk((kt + 1) * BK + 32);    // hi chunk of next tile
        mfma_half(cur, 1);
        if (more) write_chunk(cur ^ 1, 1);           // consume hi (same iter)

        __syncthreads();
    }

    // ---- norms: reduce partials across the 8 threads sharing each row ----
    // (row-sharing threads differ in tid bits {0,4,5} under the remap)
#pragma unroll
    for (int si = 0; si < 3; ++si) {
        const int s = (si == 0) ? 1 : (si == 1) ? 16 : 32;
#pragma unroll
        for (int t = 0; t < 4; ++t) {
            nA[t] += __shfl_xor(nA[t], s);
            nB[t] += __shfl_xor(nB[t], s);
        }
    }
    if ((tid & 49) == 0) {   // bits 0,4,5 zero -> one writer per row
#pragma unroll
        for (int t = 0; t < 4; ++t) {
            anrm[srow + 64 * t] = nA[t];
            bnrm[srow + 64 * t] = nB[t];
        }
    }
    __syncthreads();   // after this barrier AsU is dead -> rowred/colred alias OK

    // ---- epilogue: d = |v|^2 - 2 dot + |l|^2, row/col mins (R11-proven) ----
    const int rgrp = (lane >> 4) * 4;
    float anorm[4][4];
#pragma unroll
    for (int fr = 0; fr < 4; ++fr)
#pragma unroll
        for (int r = 0; r < 4; ++r)
            anorm[fr][r] = anrm[wrow * 64 + fr * 16 + rgrp + r];
    float bnorm[8];
#pragma unroll
    for (int fc = 0; fc < 8; ++fc)
        bnorm[fc] = bnrm[wcol * 128 + fc * 16 + lr];

    float rmin[4][4];
    float cmin[8];
#pragma unroll
    for (int fr = 0; fr < 4; ++fr)
#pragma unroll
        for (int r = 0; r < 4; ++r) rmin[fr][r] = INFINITY;
#pragma unroll
    for (int fc = 0; fc < 8; ++fc) cmin[fc] = INFINITY;

#pragma unroll
    for (int fr = 0; fr < 4; ++fr)
#pragma unroll
        for (int fc = 0; fc < 8; ++fc)
#pragma unroll
            for (int r = 0; r < 4; ++r) {
                float d = anorm[fr][r] - 2.0f * acc[fr][fc][r] + bnorm[fc];
                rmin[fr][r] = fminf(rmin[fr][r], d);
                cmin[fc] = fminf(cmin[fc], d);
            }

    // row-min across the 16 lanes holding a fragment's 16 cols
#pragma unroll
    for (int fr = 0; fr < 4; ++fr)
#pragma unroll
        for (int r = 0; r < 4; ++r) {
#pragma unroll
            for (int off = 1; off < 16; off <<= 1)
                rmin[fr][r] = fminf(rmin[fr][r], __shfl_xor(rmin[fr][r], off));
        }
    // col-min across the 4 row-groups (lane>>4)
#pragma unroll
    for (int fc = 0; fc < 8; ++fc) {
#pragma unroll
        for (int off = 16; off < 64; off <<= 1)
            cmin[fc] = fminf(cmin[fc], __shfl_xor(cmin[fc], off));
    }

    if ((lane & 15) == 0) {
#pragma unroll
        for (int fr = 0; fr < 4; ++fr)
#pragma unroll
            for (int r = 0; r < 4; ++r)
                rowred[wcol * TMM + wrow * 64 + fr * 16 + rgrp + r] = rmin[fr][r];
    }
    if (lane < 16) {
#pragma unroll
        for (int fc = 0; fc < 8; ++fc)
            colred[wrow * TNN + wcol * 128 + fc * 16 + lane] = cmin[fc];
    }
    __syncthreads();
    if (tid < TMM) {
        rowpart[((size_t)(b * 2 + nt)) * NV + mt * TMM + tid] =
            fminf(rowred[tid], rowred[TMM + tid]);
    } else {
        int c2 = tid - TMM;
        float m = INFINITY;
#pragma unroll
        for (int k = 0; k < 4; ++k) m = fminf(m, colred[k * TNN + c2]);
        colpart[((size_t)(b * 4 + mt)) * NL + nt * TNN + c2] = m;
    }
}

// ---------------- final reduce ----------------------------------------------
__global__ __launch_bounds__(256) void reduce2_kernel(
    const float* __restrict__ rowpart, const float* __restrict__ colpart,
    float* __restrict__ out) {
    int b = blockIdx.x;
    int tid = threadIdx.x;
    float s = 0.0f;
    for (int r = tid; r < NV; r += 256) {
        float m = fminf(rowpart[((size_t)(b * 2 + 0)) * NV + r],
                        rowpart[((size_t)(b * 2 + 1)) * NV + r]);
        s += m * (1.0f / NV);
    }
    for (int c = tid; c < NL; c += 256) {
        float m = INFINITY;
#pragma unroll
        for (int mt = 0; mt < 4; mt++)
            m = fminf(m, colpart[((size_t)(b * 4 + mt)) * NL + c]);
        s += m * (1.0f / NL);
    }
    __shared__ float red[4];
#pragma unroll
    for (int off = 32; off > 0; off >>= 1) s += __shfl_down(s, off);
    if ((tid & 63) == 0) red[tid >> 6] = s;
    __syncthreads();
    if (tid == 0) out[b] = red[0] + red[1] + red[2] + red[3];
}

// ============================================================================
extern "C" void kernel_launch(void* const* d_in, const int* in_sizes, int n_in,
                              void* d_out, int out_size, void* d_ws, size_t ws_size,
                              hipStream_t stream) {
    const float* video = (const float*)d_in[0];  // [64,1024,512] fp32
    const float* lang = (const float*)d_in[1];   // [64,512,512] fp32
    float* out = (float*)d_out;                  // [64]

    float* rowpart = (float*)d_ws;                      // 64*2*1024 floats (0.5 MB)
    float* colpart = rowpart + (size_t)BATCH * 2 * NV;  // 64*4*512 floats (0.5 MB)

    fused_distmin_kernel<<<dim3(512), 512, 0, stream>>>(video, lang, rowpart, colpart);
    reduce2_kernel<<<BATCH, 256, 0, stream>>>(rowpart, colpart, out);
}

// Round 14
// 66.388 us; speedup vs baseline: 2.0216x; 1.1464x over previous
//
#include <hip/hip_runtime.h>
#include <math.h>

#define BATCH 64
#define NV 1024
#define NL 512
#define DIM 512
#define TMM 256
#define TNN 256
#define BK 32
#define NKT (DIM / BK)   // 16 K-iterations

typedef __bf16 bf16x8 __attribute__((ext_vector_type(8)));
typedef __bf16 bf16x4 __attribute__((ext_vector_type(4)));
typedef float f32x4 __attribute__((ext_vector_type(4)));

// =====================================================================
// R14 = exact R11 restore (best measured: 66.5 us wall).
// Fused kernel: fp32 load -> (norms, bf16 convert) -> LDS -> MFMA GEMM
// -> distance epilogue -> row/col min partials.
// 256x256 tile, 512 threads = 8 waves as 4x2 of 64x128 wave-tiles
// (acc[4][8] = 128 regs/wave).
//
// Final configuration rationale (R3-R13 exoneration matrix):
//  - occupancy 43%<->22%: no effect (R9 vs R11)
//  - bank conflicts 9.4M<->0: no effect (R7 vs R9; lane remap kept)
//  - cache traffic 804<->536 MB: no effect (R9 vs R11; big tile kept)
//  - chain count 16<->8 iters: NEGATIVE (R13; BK=32 kept)
//  - cross-barrier pipelining: register-infeasible with fused cvt+norm
//    (R4 spill, R8 occupancy loss, R12 spill — envelope is 128 unified
//    regs/wave at 8 waves; staging live ranges must not cross barriers)
//  - launch_bounds(512,2) is the only proven-safe spelling (R6, R10)
// =====================================================================
__global__ __launch_bounds__(512, 2) void fused_distmin_kernel(
    const float* __restrict__ video, const float* __restrict__ lang,
    float* __restrict__ rowpart, float* __restrict__ colpart) {
    // Octet-major LDS: slab o in [0,4) holds k = [o*8, o*8+8) for all rows,
    // 16B per (o,row) entry. b128 frag reads and b64 writes bank-even.
    __shared__ __align__(16) ushort AsU[2][4][TMM][8];  // 32 KB
    __shared__ __align__(16) ushort BsU[2][4][TNN][8];  // 32 KB
    __shared__ float anrm[TMM], bnrm[TNN];              // 2 KB
    // Epilogue scratch aliased onto AsU (dead after last MFMA + barrier).
    float* rowred = (float*)AsU;             // [2][TMM] = 2 KB
    float* colred = (float*)AsU + 2 * TMM;   // [4][TNN] = 4 KB

    // XCD-aware swizzle: nwg = 512 = 8 XCD * 64; each XCD gets 8 whole
    // batches (8 blocks/batch).
    const int wg = ((blockIdx.x & 7) << 6) | (blockIdx.x >> 3);
    const int b = wg >> 3;          // 64 batches
    const int mt = (wg >> 1) & 3;   // 4 video row-blocks of 256
    const int nt = wg & 1;          // 2 lang col-blocks of 256

    const int tid = threadIdx.x;
    const int lane = tid & 63;
    const int w = tid >> 6;         // 0..7
    const int wrow = w >> 1;        // 0..3  (64-row band)
    const int wcol = w & 1;         // 0..1  (128-col band)
    const int lr = lane & 15;
    const int g = lane >> 4;        // k-octet for fragment reads

    // staging geometry (bank-even lane remap, R8-proven):
    const int half = tid & 1;            // 8B half of the 16B entry
    const int o_sl = (tid >> 4) & 3;     // LDS slab / k-octet
    const int srow = ((tid >> 6) << 3) + ((tid >> 1) & 7);  // 0..63
    const int skq = o_sl * 2 + half;     // k-quad in [0,8)

    const float* Ath = video + ((size_t)b * NV + (size_t)mt * TMM + srow) * DIM + skq * 4;
    const float* Bth = lang + ((size_t)b * NL + (size_t)nt * TNN + srow) * DIM + skq * 4;

    float nA[4] = {0.f, 0.f, 0.f, 0.f};   // rows srow + 64t
    float nB[4] = {0.f, 0.f, 0.f, 0.f};

    f32x4 acc[4][8];
#pragma unroll
    for (int i = 0; i < 4; i++)
#pragma unroll
        for (int j = 0; j < 8; j++) acc[i][j] = (f32x4){0.f, 0.f, 0.f, 0.f};

    float4 va[4], vb[4];

    auto load_chunk = [&](int k0) {
#pragma unroll
        for (int t = 0; t < 4; ++t) {
            va[t] = *(const float4*)(Ath + (size_t)t * 64 * DIM + k0);
            vb[t] = *(const float4*)(Bth + (size_t)t * 64 * DIM + k0);
        }
    };
    auto write_chunk = [&](int buf) {
#pragma unroll
        for (int t = 0; t < 4; ++t) {
            float4 v = va[t];
            nA[t] += v.x * v.x + v.y * v.y + v.z * v.z + v.w * v.w;
            bf16x4 p = {(__bf16)v.x, (__bf16)v.y, (__bf16)v.z, (__bf16)v.w};
            *(bf16x4*)&AsU[buf][o_sl][srow + 64 * t][half * 4] = p;
            float4 u = vb[t];
            nB[t] += u.x * u.x + u.y * u.y + u.z * u.z + u.w * u.w;
            bf16x4 q = {(__bf16)u.x, (__bf16)u.y, (__bf16)u.z, (__bf16)u.w};
            *(bf16x4*)&BsU[buf][o_sl][srow + 64 * t][half * 4] = q;
        }
    };

    // prologue: stage k-tile 0 into buf 0
    load_chunk(0);
    write_chunk(0);
    __syncthreads();

    // R7-proven cadence: loads issued at iter top, consumed (write) after
    // MFMA in the SAME iteration -> no load live across the barrier.
    for (int kt = 0; kt < NKT; ++kt) {
        const int cur = kt & 1;
        const bool more = (kt + 1) < NKT;
        if (more) load_chunk((kt + 1) * BK);

        bf16x8 av[4], bv[8];
#pragma unroll
        for (int fr = 0; fr < 4; ++fr)
            av[fr] = *(const bf16x8*)&AsU[cur][g][wrow * 64 + fr * 16 + lr][0];
#pragma unroll
        for (int fc = 0; fc < 8; ++fc)
            bv[fc] = *(const bf16x8*)&BsU[cur][g][wcol * 128 + fc * 16 + lr][0];
#pragma unroll
        for (int fr = 0; fr < 4; ++fr)
#pragma unroll
            for (int fc = 0; fc < 8; ++fc)
                acc[fr][fc] = __builtin_amdgcn_mfma_f32_16x16x32_bf16(
                    av[fr], bv[fc], acc[fr][fc], 0, 0, 0);

        if (more) write_chunk(cur ^ 1);   // cvt + norm-fma + ds_write after MFMA
        __syncthreads();
    }

    // ---- norms: reduce partials across the 8 threads sharing each row ----
    // (row-sharing threads differ in tid bits {0,4,5} under the remap)
#pragma unroll
    for (int si = 0; si < 3; ++si) {
        const int s = (si == 0) ? 1 : (si == 1) ? 16 : 32;
#pragma unroll
        for (int t = 0; t < 4; ++t) {
            nA[t] += __shfl_xor(nA[t], s);
            nB[t] += __shfl_xor(nB[t], s);
        }
    }
    if ((tid & 49) == 0) {   // bits 0,4,5 zero -> one writer per row
#pragma unroll
        for (int t = 0; t < 4; ++t) {
            anrm[srow + 64 * t] = nA[t];
            bnrm[srow + 64 * t] = nB[t];
        }
    }
    __syncthreads();   // after this barrier AsU is dead -> rowred/colred alias OK

    // ---- epilogue: d = |v|^2 - 2 dot + |l|^2, row/col mins ----
    const int rgrp = (lane >> 4) * 4;
    float anorm[4][4];
#pragma unroll
    for (int fr = 0; fr < 4; ++fr)
#pragma unroll
        for (int r = 0; r < 4; ++r)
            anorm[fr][r] = anrm[wrow * 64 + fr * 16 + rgrp + r];
    float bnorm[8];
#pragma unroll
    for (int fc = 0; fc < 8; ++fc)
        bnorm[fc] = bnrm[wcol * 128 + fc * 16 + lr];

    float rmin[4][4];
    float cmin[8];
#pragma unroll
    for (int fr = 0; fr < 4; ++fr)
#pragma unroll
        for (int r = 0; r < 4; ++r) rmin[fr][r] = INFINITY;
#pragma unroll
    for (int fc = 0; fc < 8; ++fc) cmin[fc] = INFINITY;

#pragma unroll
    for (int fr = 0; fr < 4; ++fr)
#pragma unroll
        for (int fc = 0; fc < 8; ++fc)
#pragma unroll
            for (int r = 0; r < 4; ++r) {
                float d = anorm[fr][r] - 2.0f * acc[fr][fc][r] + bnorm[fc];
                rmin[fr][r] = fminf(rmin[fr][r], d);
                cmin[fc] = fminf(cmin[fc], d);
            }

    // row-min across the 16 lanes holding a fragment's 16 cols
#pragma unroll
    for (int fr = 0; fr < 4; ++fr)
#pragma unroll
        for (int r = 0; r < 4; ++r) {
#pragma unroll
            for (int off = 1; off < 16; off <<= 1)
                rmin[fr][r] = fminf(rmin[fr][r], __shfl_xor(rmin[fr][r], off));
        }
    // col-min across the 4 row-groups (lane>>4)
#pragma unroll
    for (int fc = 0; fc < 8; ++fc) {
#pragma unroll
        for (int off = 16; off < 64; off <<= 1)
            cmin[fc] = fminf(cmin[fc], __shfl_xor(cmin[fc], off));
    }

    if ((lane & 15) == 0) {
#pragma unroll
        for (int fr = 0; fr < 4; ++fr)
#pragma unroll
            for (int r = 0; r < 4; ++r)
                rowred[wcol * TMM + wrow * 64 + fr * 16 + rgrp + r] = rmin[fr][r];
    }
    if (lane < 16) {
#pragma unroll
        for (int fc = 0; fc < 8; ++fc)
            colred[wrow * TNN + wcol * 128 + fc * 16 + lane] = cmin[fc];
    }
    __syncthreads();
    if (tid < TMM) {
        rowpart[((size_t)(b * 2 + nt)) * NV + mt * TMM + tid] =
            fminf(rowred[tid], rowred[TMM + tid]);
    } else {
        int c2 = tid - TMM;
        float m = INFINITY;
#pragma unroll
        for (int k = 0; k < 4; ++k) m = fminf(m, colred[k * TNN + c2]);
        colpart[((size_t)(b * 4 + mt)) * NL + nt * TNN + c2] = m;
    }
}

// ---------------- final reduce ----------------------------------------------
__global__ __launch_bounds__(256) void reduce2_kernel(
    const float* __restrict__ rowpart, const float* __restrict__ colpart,
    float* __restrict__ out) {
    int b = blockIdx.x;
    int tid = threadIdx.x;
    float s = 0.0f;
    for (int r = tid; r < NV; r += 256) {
        float m = fminf(rowpart[((size_t)(b * 2 + 0)) * NV + r],
                        rowpart[((size_t)(b * 2 + 1)) * NV + r]);
        s += m * (1.0f / NV);
    }
    for (int c = tid; c < NL; c += 256) {
        float m = INFINITY;
#pragma unroll
        for (int mt = 0; mt < 4; mt++)
            m = fminf(m, colpart[((size_t)(b * 4 + mt)) * NL + c]);
        s += m * (1.0f / NL);
    }
    __shared__ float red[4];
#pragma unroll
    for (int off = 32; off > 0; off >>= 1) s += __shfl_down(s, off);
    if ((tid & 63) == 0) red[tid >> 6] = s;
    __syncthreads();
    if (tid == 0) out[b] = red[0] + red[1] + red[2] + red[3];
}

// ============================================================================
extern "C" void kernel_launch(void* const* d_in, const int* in_sizes, int n_in,
                              void* d_out, int out_size, void* d_ws, size_t ws_size,
                              hipStream_t stream) {
    const float* video = (const float*)d_in[0];  // [64,1024,512] fp32
    const float* lang = (const float*)d_in[1];   // [64,512,512] fp32
    float* out = (float*)d_out;                  // [64]

    float* rowpart = (float*)d_ws;                      // 64*2*1024 floats (0.5 MB)
    float* colpart = rowpart + (size_t)BATCH * 2 * NV;  // 64*4*512 floats (0.5 MB)

    fused_distmin_kernel<<<dim3(512), 512, 0, stream>>>(video, lang, rowpart, colpart);
    reduce2_kernel<<<BATCH, 256, 0, stream>>>(rowpart, colpart, out);
}